// Round 5
// baseline (1126.692 us; speedup 1.0000x reference)
//
#include <hip/hip_runtime.h>
#include <hip/hip_bf16.h>

#define B_  32
#define S_  4096
#define H_  1024
#define NH_ 16
#define DK_ 64
#define NCH 16                            // chunks of 256 rows
#define ROWS 256
#define TILE 8                            // rows per LDS tile
#define NT (ROWS / TILE)                  // 32 tiles per chunk

// workspace layout (float offsets)
#define Q_OFF  0
#define T_OFF  (Q_OFF + B_*H_)            // q: B*H
#define C_OFF  (T_OFF + B_*NH_*H_)        // t: B*NH*H
#define YP_OFF (C_OFF + B_*NH_)           // c: B*NH
#define ML_OFF (YP_OFF + NCH*B_*NH_*H_)   // y_part: NCH*B*NH*H (32 MB)
#define OP_OFF (ML_OFF + NCH*B_*2*NH_)    // ml stats: NCH*B*2*NH

#define DOT4(a, v) ((a).x*(v).x + (a).y*(v).y + (a).z*(v).z + (a).w*(v).w)

// ---------------- kernel 1: q[b,i] = x[b,S-1,:] . Wq[i,:] + bq[i] ----------
__global__ __launch_bounds__(256) void k_q(const float* __restrict__ x,
                                           const float* __restrict__ Wq,
                                           const float* __restrict__ bq,
                                           float* __restrict__ q) {
  __shared__ __align__(16) float xl[4 * H_];
  int islab = blockIdx.x, bg = blockIdx.y, tid = threadIdx.x;
  #pragma unroll
  for (int k = 0; k < 4; ++k) {
    int idx4 = k * 256 + tid;
    int bl = idx4 >> 8, col4 = idx4 & 255;
    *(float4*)&xl[bl * H_ + col4 * 4] =
        *(const float4*)(x + (((size_t)(bg * 4 + bl)) * S_ + (S_ - 1)) * H_ + col4 * 4);
  }
  __syncthreads();
  int i = islab * 256 + tid;
  const float* w = Wq + (size_t)i * H_;
  float acc[4] = {0.f, 0.f, 0.f, 0.f};
  for (int j = 0; j < H_; j += 4) {
    float4 wv = *(const float4*)&w[j];
    #pragma unroll
    for (int bl = 0; bl < 4; ++bl) {
      float4 xv = *(const float4*)&xl[bl * H_ + j];
      acc[bl] += DOT4(xv, wv);
    }
  }
  float bias = bq[i];
  #pragma unroll
  for (int bl = 0; bl < 4; ++bl)
    q[(size_t)(bg * 4 + bl) * H_ + i] = acc[bl] + bias;
}

// -------- kernel 2: t[b,h,j] = sum_d q[b,h,d]*Wk[h*64+d, j]; c[b,h]=q.bk ---
__global__ __launch_bounds__(256) void k_t(const float* __restrict__ q,
                                           const float* __restrict__ Wk,
                                           const float* __restrict__ bk,
                                           float* __restrict__ t,
                                           float* __restrict__ c) {
  __shared__ __align__(16) float qh[B_ * DK_];   // 8 KB
  __shared__ __align__(16) float bkh[DK_];
  int js = blockIdx.x, h = blockIdx.y, tid = threadIdx.x;
  #pragma unroll
  for (int k = 0; k < 2; ++k) {
    int idx4 = k * 256 + tid;
    int bl = idx4 >> 4, d4 = idx4 & 15;
    *(float4*)&qh[bl * DK_ + d4 * 4] =
        *(const float4*)(q + (size_t)bl * H_ + h * DK_ + d4 * 4);
  }
  if (tid < 16)
    *(float4*)&bkh[tid * 4] = *(const float4*)(bk + h * DK_ + tid * 4);
  __syncthreads();

  if (js == 0 && tid < B_) {
    float cc = 0.f;
    for (int d = 0; d < DK_; ++d) cc += qh[tid * DK_ + d] * bkh[d];
    c[tid * NH_ + h] = cc;
  }

  int j = js * 256 + tid;
  float acc[B_];
  #pragma unroll
  for (int bl = 0; bl < B_; ++bl) acc[bl] = 0.f;
  for (int d = 0; d < DK_; ++d) {
    float wv = Wk[((size_t)(h * DK_ + d)) * H_ + j];
    #pragma unroll
    for (int bl = 0; bl < B_; ++bl) acc[bl] += qh[bl * DK_ + d] * wv;
  }
  #pragma unroll
  for (int bl = 0; bl < B_; ++bl)
    t[((size_t)(bl * NH_ + h)) * H_ + j] = acc[bl];
}

// ---- kernel 3 (fused flash pass): one read of x computes scores + online
// softmax + weighted x-accumulation.
// Block = (chunk, b), 256 thr. Lane role phase A: (h = wave*4 + (lane>>4),
// cg = lane&15) -> 64-col slice dot; shfl_xor reduce over cg.
// Phase B: thread owns cols tid*4..+3, acc yacc[16][4].
__global__ __launch_bounds__(256, 2) void k_flash(const float* __restrict__ x,
                                                  const float* __restrict__ t,
                                                  const float* __restrict__ c,
                                                  float* __restrict__ ypart,
                                                  float* __restrict__ mlpart) {
  __shared__ __align__(16) float xb[2][TILE * H_];   // 2 x 32 KB
  __shared__ __align__(16) float eL[TILE][NH_];
  __shared__ float facL[NH_], mL[NH_], lL[NH_], cL[NH_];

  int ch = blockIdx.x, b = blockIdx.y, tid = threadIdx.x;
  int wv = tid >> 6, ln = tid & 63;
  int hh = ln >> 4, cg = ln & 15;
  int h = wv * 4 + hh;

  const float* xg = x + ((size_t)b * S_ + (size_t)ch * ROWS) * H_;

  // t fragment: head h, cols cg*64..cg*64+63, stored in ROTATED order so the
  // phase-A loop is statically indexed while addresses spread LDS banks.
  float4 tf[16];
  const float* tg = t + ((size_t)b * NH_ + h) * H_ + cg * 64;
  #pragma unroll
  for (int jj = 0; jj < 16; ++jj)
    tf[jj] = *(const float4*)(tg + ((jj + cg) & 15) * 4);

  if (tid < NH_) {
    mL[tid] = -3.4e38f;
    lL[tid] = 0.f;
    cL[tid] = c[b * NH_ + tid];
  }

  float4 ya[NH_];
  #pragma unroll
  for (int h2 = 0; h2 < NH_; ++h2) { ya[h2].x = ya[h2].y = ya[h2].z = ya[h2].w = 0.f; }

  // prologue: tile 0 -> xb[0]
  float4 px[8];
  #pragma unroll
  for (int k = 0; k < 8; ++k) {
    int f = tid + k * 256;
    px[k] = *(const float4*)(xg + (size_t)(f >> 8) * H_ + (f & 255) * 4);
  }
  #pragma unroll
  for (int k = 0; k < 8; ++k) {
    int f = tid + k * 256;
    *(float4*)&xb[0][(f >> 8) * H_ + (f & 255) * 4] = px[k];
  }
  __syncthreads();

  float cL_h = cL[h];

  #pragma unroll 1
  for (int tl = 0; tl < NT; ++tl) {
    int cur = tl & 1;
    // prefetch next tile into registers (overlaps with phase A/B)
    int ntl = (tl + 1 < NT) ? tl + 1 : tl;
    const float* xn = xg + (size_t)ntl * TILE * H_;
    #pragma unroll
    for (int k = 0; k < 8; ++k) {
      int f = tid + k * 256;
      px[k] = *(const float4*)(xn + (size_t)(f >> 8) * H_ + (f & 255) * 4);
    }

    // ---- phase A: scores for TILE rows, head h, cols cg*64..+63 ----
    float scr[TILE];
    #pragma unroll
    for (int s = 0; s < TILE; ++s) scr[s] = 0.f;
    #pragma unroll
    for (int jj = 0; jj < 16; ++jj) {
      int cc = cg * 64 + ((jj + cg) & 15) * 4;
      float4 tv = tf[jj];
      #pragma unroll
      for (int s = 0; s < TILE; ++s) {
        float4 xv = *(const float4*)&xb[cur][s * H_ + cc];
        scr[s] += DOT4(xv, tv);
      }
    }
    #pragma unroll
    for (int s = 0; s < TILE; ++s) {
      float a = scr[s];
      a += __shfl_xor(a, 1);
      a += __shfl_xor(a, 2);
      a += __shfl_xor(a, 4);
      a += __shfl_xor(a, 8);
      scr[s] = (a + cL_h) * 0.125f;
    }
    // online-softmax bookkeeping (redundant across the 16 cg lanes)
    float tmax = scr[0];
    #pragma unroll
    for (int s = 1; s < TILE; ++s) tmax = fmaxf(tmax, scr[s]);
    float mold = mL[h];
    float mnew = fmaxf(mold, tmax);
    float fac = __expf(mold - mnew);
    float es[TILE];
    float sume = 0.f;
    #pragma unroll
    for (int s = 0; s < TILE; ++s) { es[s] = __expf(scr[s] - mnew); sume += es[s]; }
    if (cg == 0) {
      mL[h] = mnew;
      lL[h] = lL[h] * fac + sume;
      facL[h] = fac;
    }
    // lane cg<TILE writes e for row cg (static-select, no dyn reg index)
    float ev = es[0];
    #pragma unroll
    for (int s = 1; s < TILE; ++s) ev = (cg == s) ? es[s] : ev;
    if (cg < TILE) eL[cg][h] = ev;
    __syncthreads();

    // ---- phase B: rescale + accumulate ----
    #pragma unroll
    for (int h2 = 0; h2 < NH_; ++h2) {
      float f2 = facL[h2];
      ya[h2].x *= f2; ya[h2].y *= f2; ya[h2].z *= f2; ya[h2].w *= f2;
    }
    #pragma unroll
    for (int s = 0; s < TILE; ++s) {
      float4 xv = *(const float4*)&xb[cur][s * H_ + tid * 4];
      #pragma unroll
      for (int h4 = 0; h4 < 4; ++h4) {
        float4 e4 = *(const float4*)&eL[s][h4 * 4];
        ya[h4*4+0].x += e4.x * xv.x; ya[h4*4+0].y += e4.x * xv.y;
        ya[h4*4+0].z += e4.x * xv.z; ya[h4*4+0].w += e4.x * xv.w;
        ya[h4*4+1].x += e4.y * xv.x; ya[h4*4+1].y += e4.y * xv.y;
        ya[h4*4+1].z += e4.y * xv.z; ya[h4*4+1].w += e4.y * xv.w;
        ya[h4*4+2].x += e4.z * xv.x; ya[h4*4+2].y += e4.z * xv.y;
        ya[h4*4+2].z += e4.z * xv.z; ya[h4*4+2].w += e4.z * xv.w;
        ya[h4*4+3].x += e4.w * xv.x; ya[h4*4+3].y += e4.w * xv.y;
        ya[h4*4+3].z += e4.w * xv.z; ya[h4*4+3].w += e4.w * xv.w;
      }
    }
    // stage prefetched tile into the other buffer
    if (tl + 1 < NT) {
      #pragma unroll
      for (int k = 0; k < 8; ++k) {
        int f = tid + k * 256;
        *(float4*)&xb[cur ^ 1][(f >> 8) * H_ + (f & 255) * 4] = px[k];
      }
    }
    __syncthreads();
  }

  // epilogue: partial y + stats
  float* yo = ypart + ((size_t)(ch * B_ + b)) * NH_ * H_ + tid * 4;
  #pragma unroll
  for (int h2 = 0; h2 < NH_; ++h2)
    *(float4*)(yo + (size_t)h2 * H_) = ya[h2];
  if (tid < NH_) {
    mlpart[((size_t)(ch * B_ + b)) * (2 * NH_) + tid * 2 + 0] = mL[tid];
    mlpart[((size_t)(ch * B_ + b)) * (2 * NH_) + tid * 2 + 1] = lL[tid];
  }
}

// -- kernel 4: y[b,h,:] = rescaled sum of y_part / denom; op = Wv.y + bv ----
__global__ __launch_bounds__(256) void k_vproj(const float* __restrict__ ypart,
                                               const float* __restrict__ mlpart,
                                               const float* __restrict__ Wv,
                                               const float* __restrict__ bv,
                                               float* __restrict__ op) {
  __shared__ __align__(16) float yl[4 * H_];
  int h = blockIdx.x, bg = blockIdx.y, tid = threadIdx.x;

  #pragma unroll
  for (int bl = 0; bl < 4; ++bl) {
    int b = bg * 4 + bl;
    float mg = -3.4e38f;
    for (int ch = 0; ch < NCH; ++ch)
      mg = fmaxf(mg, mlpart[((size_t)(ch * B_ + b)) * (2 * NH_) + h * 2]);
    float L = 0.f;
    float4 acc; acc.x = acc.y = acc.z = acc.w = 0.f;
    for (int ch = 0; ch < NCH; ++ch) {
      float mc = mlpart[((size_t)(ch * B_ + b)) * (2 * NH_) + h * 2 + 0];
      float lc = mlpart[((size_t)(ch * B_ + b)) * (2 * NH_) + h * 2 + 1];
      float w = __expf(mc - mg);
      L += w * lc;
      float4 v = *(const float4*)(ypart +
          ((size_t)(ch * B_ + b)) * NH_ * H_ + (size_t)h * H_ + tid * 4);
      acc.x += w * v.x; acc.y += w * v.y; acc.z += w * v.z; acc.w += w * v.w;
    }
    float inv = 1.f / L;
    acc.x *= inv; acc.y *= inv; acc.z *= inv; acc.w *= inv;
    *(float4*)&yl[bl * H_ + tid * 4] = acc;
  }
  __syncthreads();

  int d = tid >> 2, p = tid & 3;
  const float* w = Wv + ((size_t)(h * DK_ + d)) * H_ + p * 256;
  float acc[4] = {0.f, 0.f, 0.f, 0.f};
  for (int jj = 0; jj < 256; jj += 4) {
    float4 wv = *(const float4*)(w + jj);
    #pragma unroll
    for (int bl = 0; bl < 4; ++bl) {
      float4 yv = *(const float4*)&yl[bl * H_ + p * 256 + jj];
      acc[bl] += DOT4(yv, wv);
    }
  }
  #pragma unroll
  for (int bl = 0; bl < 4; ++bl) {
    acc[bl] += __shfl_xor(acc[bl], 1);
    acc[bl] += __shfl_xor(acc[bl], 2);
  }
  if (p == 0) {
    float bias = bv[h * DK_ + d];
    #pragma unroll
    for (int bl = 0; bl < 4; ++bl)
      op[(size_t)(bg * 4 + bl) * H_ + h * DK_ + d] = acc[bl] + bias;
  }
}

// -------- kernel 5: out[b,i] = Wo[i,:].out_pre[b,:] + bo[i] ----------------
__global__ __launch_bounds__(256) void k_out(const float* __restrict__ op,
                                             const float* __restrict__ Wo,
                                             const float* __restrict__ bo,
                                             float* __restrict__ out) {
  __shared__ __align__(16) float ul[4 * H_];
  int islab = blockIdx.x, bg = blockIdx.y, tid = threadIdx.x;
  #pragma unroll
  for (int k = 0; k < 4; ++k) {
    int idx4 = k * 256 + tid;
    int bl = idx4 >> 8, col4 = idx4 & 255;
    *(float4*)&ul[bl * H_ + col4 * 4] =
        *(const float4*)(op + (size_t)(bg * 4 + bl) * H_ + col4 * 4);
  }
  __syncthreads();
  int i = islab * 256 + tid;
  const float* w = Wo + (size_t)i * H_;
  float acc[4] = {0.f, 0.f, 0.f, 0.f};
  for (int j = 0; j < H_; j += 4) {
    float4 wv = *(const float4*)&w[j];
    #pragma unroll
    for (int bl = 0; bl < 4; ++bl) {
      float4 uv = *(const float4*)&ul[bl * H_ + j];
      acc[bl] += DOT4(uv, wv);
    }
  }
  float bias = bo[i];
  #pragma unroll
  for (int bl = 0; bl < 4; ++bl)
    out[(size_t)(bg * 4 + bl) * H_ + i] = acc[bl] + bias;
}

extern "C" void kernel_launch(void* const* d_in, const int* in_sizes, int n_in,
                              void* d_out, int out_size, void* d_ws, size_t ws_size,
                              hipStream_t stream) {
  const float* x  = (const float*)d_in[0];
  const float* Wq = (const float*)d_in[1];
  const float* bq = (const float*)d_in[2];
  const float* Wk = (const float*)d_in[3];
  const float* bk = (const float*)d_in[4];
  const float* Wv = (const float*)d_in[5];
  const float* bv = (const float*)d_in[6];
  const float* Wo = (const float*)d_in[7];
  const float* bo = (const float*)d_in[8];
  float* out = (float*)d_out;
  float* ws = (float*)d_ws;

  float* q  = ws + Q_OFF;
  float* t  = ws + T_OFF;
  float* c  = ws + C_OFF;
  float* yp = ws + YP_OFF;
  float* ml = ws + ML_OFF;
  float* op = ws + OP_OFF;

  k_q<<<dim3(4, B_ / 4), 256, 0, stream>>>(x, Wq, bq, q);
  k_t<<<dim3(4, NH_), 256, 0, stream>>>(q, Wk, bk, t, c);
  k_flash<<<dim3(NCH, B_), 256, 0, stream>>>(x, t, c, yp, ml);
  k_vproj<<<dim3(NH_, B_ / 4), 256, 0, stream>>>(yp, ml, Wv, bv, op);
  k_out<<<dim3(4, B_ / 4), 256, 0, stream>>>(op, Wo, bo, out);
}

// Round 6
// 504.439 us; speedup vs baseline: 2.2336x; 2.2336x over previous
//
#include <hip/hip_runtime.h>
#include <hip/hip_bf16.h>

#define B_  32
#define S_  4096
#define H_  1024
#define NH_ 16
#define DK_ 64
#define NCH 16                            // chunks of 256 rows
#define ROWS 256
#define TILE 8                            // rows per LDS tile
#define NT (ROWS / TILE)                  // 32 tiles per chunk

// workspace layout (float offsets)
#define Q_OFF  0
#define T_OFF  (Q_OFF + B_*H_)            // q: B*H
#define C_OFF  (T_OFF + B_*NH_*H_)        // t: B*NH*H
#define YP_OFF (C_OFF + B_*NH_)           // c: B*NH
#define ML_OFF (YP_OFF + NCH*B_*NH_*H_)   // y_part: NCH*B*NH*H (32 MB)
#define OP_OFF (ML_OFF + NCH*B_*2*NH_)    // ml stats: NCH*B*2*NH

#define DOT4(a, v) ((a).x*(v).x + (a).y*(v).y + (a).z*(v).z + (a).w*(v).w)

// async global->LDS 16B per lane; lptr must be wave-uniform base
__device__ __forceinline__ void load_lds16(const float* g, float* l) {
  __builtin_amdgcn_global_load_lds(
      (const __attribute__((address_space(1))) void*)g,
      (__attribute__((address_space(3))) void*)l, 16, 0, 0);
}

// ---------------- kernel 1: q[b,i] = x[b,S-1,:] . Wq[i,:] + bq[i] ----------
__global__ __launch_bounds__(256) void k_q(const float* __restrict__ x,
                                           const float* __restrict__ Wq,
                                           const float* __restrict__ bq,
                                           float* __restrict__ q) {
  __shared__ __align__(16) float xl[4 * H_];
  int islab = blockIdx.x, bg = blockIdx.y, tid = threadIdx.x;
  #pragma unroll
  for (int k = 0; k < 4; ++k) {
    int idx4 = k * 256 + tid;
    int bl = idx4 >> 8, col4 = idx4 & 255;
    *(float4*)&xl[bl * H_ + col4 * 4] =
        *(const float4*)(x + (((size_t)(bg * 4 + bl)) * S_ + (S_ - 1)) * H_ + col4 * 4);
  }
  __syncthreads();
  int i = islab * 256 + tid;
  const float* w = Wq + (size_t)i * H_;
  float acc[4] = {0.f, 0.f, 0.f, 0.f};
  for (int j = 0; j < H_; j += 4) {
    float4 wv = *(const float4*)&w[j];
    #pragma unroll
    for (int bl = 0; bl < 4; ++bl) {
      float4 xv = *(const float4*)&xl[bl * H_ + j];
      acc[bl] += DOT4(xv, wv);
    }
  }
  float bias = bq[i];
  #pragma unroll
  for (int bl = 0; bl < 4; ++bl)
    q[(size_t)(bg * 4 + bl) * H_ + i] = acc[bl] + bias;
}

// -------- kernel 2: t[b,h,j] = sum_d q[b,h,d]*Wk[h*64+d, j]; c[b,h]=q.bk ---
__global__ __launch_bounds__(256) void k_t(const float* __restrict__ q,
                                           const float* __restrict__ Wk,
                                           const float* __restrict__ bk,
                                           float* __restrict__ t,
                                           float* __restrict__ c) {
  __shared__ __align__(16) float qh[B_ * DK_];   // 8 KB
  __shared__ __align__(16) float bkh[DK_];
  int js = blockIdx.x, h = blockIdx.y, tid = threadIdx.x;
  #pragma unroll
  for (int k = 0; k < 2; ++k) {
    int idx4 = k * 256 + tid;
    int bl = idx4 >> 4, d4 = idx4 & 15;
    *(float4*)&qh[bl * DK_ + d4 * 4] =
        *(const float4*)(q + (size_t)bl * H_ + h * DK_ + d4 * 4);
  }
  if (tid < 16)
    *(float4*)&bkh[tid * 4] = *(const float4*)(bk + h * DK_ + tid * 4);
  __syncthreads();

  if (js == 0 && tid < B_) {
    float cc = 0.f;
    for (int d = 0; d < DK_; ++d) cc += qh[tid * DK_ + d] * bkh[d];
    c[tid * NH_ + h] = cc;
  }

  int j = js * 256 + tid;
  float acc[B_];
  #pragma unroll
  for (int bl = 0; bl < B_; ++bl) acc[bl] = 0.f;
  for (int d = 0; d < DK_; ++d) {
    float wv = Wk[((size_t)(h * DK_ + d)) * H_ + j];
    #pragma unroll
    for (int bl = 0; bl < B_; ++bl) acc[bl] += qh[bl * DK_ + d] * wv;
  }
  #pragma unroll
  for (int bl = 0; bl < B_; ++bl)
    t[((size_t)(bl * NH_ + h)) * H_ + j] = acc[bl];
}

// ---- kernel 3 (fused flash pass): one read of x computes scores + online
// softmax + weighted x-accumulation. x staged via async global_load_lds
// double-buffer (no VGPR cost). Natural register allocation (~170 VGPR,
// no spill; LDS caps residency at 2 blocks/CU anyway).
__global__ __launch_bounds__(256) void k_flash(const float* __restrict__ x,
                                               const float* __restrict__ t,
                                               const float* __restrict__ c,
                                               float* __restrict__ ypart,
                                               float* __restrict__ mlpart) {
  __shared__ __align__(16) float xb[2][TILE * H_];   // 2 x 32 KB
  __shared__ __align__(16) float eL[TILE][NH_];
  __shared__ float facL[NH_], mL[NH_], lL[NH_], cL[NH_];

  int ch = blockIdx.x, b = blockIdx.y, tid = threadIdx.x;
  int wv = tid >> 6, ln = tid & 63;
  int hh = ln >> 4, cg = ln & 15;
  int h = wv * 4 + hh;
  int lseg = (tid >> 6) * 256;          // wave's 1KB LDS segment (floats)
  int lsub = (tid & 63) * 4;            // lane's float offset in segment

  const float* xg = x + ((size_t)b * S_ + (size_t)ch * ROWS) * H_;

  // t fragment: head h, cols cg*64..cg*64+63, ROTATED order (bank spread).
  float4 tf[16];
  const float* tg = t + ((size_t)b * NH_ + h) * H_ + cg * 64;
  #pragma unroll
  for (int jj = 0; jj < 16; ++jj)
    tf[jj] = *(const float4*)(tg + ((jj + cg) & 15) * 4);

  if (tid < NH_) {
    mL[tid] = -3.4e38f;
    lL[tid] = 0.f;
    cL[tid] = c[b * NH_ + tid];
  }

  float4 ya[NH_];
  #pragma unroll
  for (int h2 = 0; h2 < NH_; ++h2) { ya[h2].x = ya[h2].y = ya[h2].z = ya[h2].w = 0.f; }

  // prologue: async-stage tile 0 -> xb[0]
  #pragma unroll
  for (int k = 0; k < 8; ++k)
    load_lds16(xg + k * 1024 + lseg + lsub, &xb[0][k * 1024 + lseg]);
  __syncthreads();

  float cL_h = cL[h];

  #pragma unroll 1
  for (int tl = 0; tl < NT; ++tl) {
    int cur = tl & 1;
    // async prefetch of next tile into the other buffer
    if (tl + 1 < NT) {
      const float* xn = xg + (size_t)(tl + 1) * TILE * H_;
      #pragma unroll
      for (int k = 0; k < 8; ++k)
        load_lds16(xn + k * 1024 + lseg + lsub, &xb[cur ^ 1][k * 1024 + lseg]);
    }

    // ---- phase A: scores for TILE rows, head h, cols cg*64..+63 ----
    float scr[TILE];
    #pragma unroll
    for (int s = 0; s < TILE; ++s) scr[s] = 0.f;
    #pragma unroll
    for (int jj = 0; jj < 16; ++jj) {
      int cc = cg * 64 + ((jj + cg) & 15) * 4;
      float4 tv = tf[jj];
      #pragma unroll
      for (int s = 0; s < TILE; ++s) {
        float4 xv = *(const float4*)&xb[cur][s * H_ + cc];
        scr[s] += DOT4(xv, tv);
      }
    }
    #pragma unroll
    for (int s = 0; s < TILE; ++s) {
      float a = scr[s];
      a += __shfl_xor(a, 1);
      a += __shfl_xor(a, 2);
      a += __shfl_xor(a, 4);
      a += __shfl_xor(a, 8);
      scr[s] = (a + cL_h) * 0.125f;
    }
    // online-softmax bookkeeping (redundant across the 16 cg lanes)
    float tmax = scr[0];
    #pragma unroll
    for (int s = 1; s < TILE; ++s) tmax = fmaxf(tmax, scr[s]);
    float mold = mL[h];
    float mnew = fmaxf(mold, tmax);
    float fac = __expf(mold - mnew);
    float es[TILE];
    float sume = 0.f;
    #pragma unroll
    for (int s = 0; s < TILE; ++s) { es[s] = __expf(scr[s] - mnew); sume += es[s]; }
    if (cg == 0) {
      mL[h] = mnew;
      lL[h] = lL[h] * fac + sume;
      facL[h] = fac;
    }
    // lane cg<TILE writes e for row cg (static-select, no dyn reg index)
    float ev = es[0];
    #pragma unroll
    for (int s = 1; s < TILE; ++s) ev = (cg == s) ? es[s] : ev;
    if (cg < TILE) eL[cg][h] = ev;
    __syncthreads();

    // ---- phase B: rescale + accumulate ----
    #pragma unroll
    for (int h2 = 0; h2 < NH_; ++h2) {
      float f2 = facL[h2];
      ya[h2].x *= f2; ya[h2].y *= f2; ya[h2].z *= f2; ya[h2].w *= f2;
    }
    #pragma unroll
    for (int s = 0; s < TILE; ++s) {
      float4 xv = *(const float4*)&xb[cur][s * H_ + tid * 4];
      #pragma unroll
      for (int h4 = 0; h4 < 4; ++h4) {
        float4 e4 = *(const float4*)&eL[s][h4 * 4];
        ya[h4*4+0].x += e4.x * xv.x; ya[h4*4+0].y += e4.x * xv.y;
        ya[h4*4+0].z += e4.x * xv.z; ya[h4*4+0].w += e4.x * xv.w;
        ya[h4*4+1].x += e4.y * xv.x; ya[h4*4+1].y += e4.y * xv.y;
        ya[h4*4+1].z += e4.y * xv.z; ya[h4*4+1].w += e4.y * xv.w;
        ya[h4*4+2].x += e4.z * xv.x; ya[h4*4+2].y += e4.z * xv.y;
        ya[h4*4+2].z += e4.z * xv.z; ya[h4*4+2].w += e4.z * xv.w;
        ya[h4*4+3].x += e4.w * xv.x; ya[h4*4+3].y += e4.w * xv.y;
        ya[h4*4+3].z += e4.w * xv.z; ya[h4*4+3].w += e4.w * xv.w;
      }
    }
    __syncthreads();   // drains async loads (compiler emits vmcnt before barrier)
  }

  // epilogue: partial y + stats
  float* yo = ypart + ((size_t)(ch * B_ + b)) * NH_ * H_ + tid * 4;
  #pragma unroll
  for (int h2 = 0; h2 < NH_; ++h2)
    *(float4*)(yo + (size_t)h2 * H_) = ya[h2];
  if (tid < NH_) {
    mlpart[((size_t)(ch * B_ + b)) * (2 * NH_) + tid * 2 + 0] = mL[tid];
    mlpart[((size_t)(ch * B_ + b)) * (2 * NH_) + tid * 2 + 1] = lL[tid];
  }
}

// -- kernel 4: y[b,h,:] = rescaled sum of y_part / denom; op = Wv.y + bv ----
__global__ __launch_bounds__(256) void k_vproj(const float* __restrict__ ypart,
                                               const float* __restrict__ mlpart,
                                               const float* __restrict__ Wv,
                                               const float* __restrict__ bv,
                                               float* __restrict__ op) {
  __shared__ __align__(16) float yl[4 * H_];
  int h = blockIdx.x, bg = blockIdx.y, tid = threadIdx.x;

  #pragma unroll
  for (int bl = 0; bl < 4; ++bl) {
    int b = bg * 4 + bl;
    float mg = -3.4e38f;
    for (int ch = 0; ch < NCH; ++ch)
      mg = fmaxf(mg, mlpart[((size_t)(ch * B_ + b)) * (2 * NH_) + h * 2]);
    float L = 0.f;
    float4 acc; acc.x = acc.y = acc.z = acc.w = 0.f;
    for (int ch = 0; ch < NCH; ++ch) {
      float mc = mlpart[((size_t)(ch * B_ + b)) * (2 * NH_) + h * 2 + 0];
      float lc = mlpart[((size_t)(ch * B_ + b)) * (2 * NH_) + h * 2 + 1];
      float w = __expf(mc - mg);
      L += w * lc;
      float4 v = *(const float4*)(ypart +
          ((size_t)(ch * B_ + b)) * NH_ * H_ + (size_t)h * H_ + tid * 4);
      acc.x += w * v.x; acc.y += w * v.y; acc.z += w * v.z; acc.w += w * v.w;
    }
    float inv = 1.f / L;
    acc.x *= inv; acc.y *= inv; acc.z *= inv; acc.w *= inv;
    *(float4*)&yl[bl * H_ + tid * 4] = acc;
  }
  __syncthreads();

  int d = tid >> 2, p = tid & 3;
  const float* w = Wv + ((size_t)(h * DK_ + d)) * H_ + p * 256;
  float acc[4] = {0.f, 0.f, 0.f, 0.f};
  for (int jj = 0; jj < 256; jj += 4) {
    float4 wv = *(const float4*)(w + jj);
    #pragma unroll
    for (int bl = 0; bl < 4; ++bl) {
      float4 yv = *(const float4*)&yl[bl * H_ + p * 256 + jj];
      acc[bl] += DOT4(yv, wv);
    }
  }
  #pragma unroll
  for (int bl = 0; bl < 4; ++bl) {
    acc[bl] += __shfl_xor(acc[bl], 1);
    acc[bl] += __shfl_xor(acc[bl], 2);
  }
  if (p == 0) {
    float bias = bv[h * DK_ + d];
    #pragma unroll
    for (int bl = 0; bl < 4; ++bl)
      op[(size_t)(bg * 4 + bl) * H_ + h * DK_ + d] = acc[bl] + bias;
  }
}

// -------- kernel 5: out[b,i] = Wo[i,:].out_pre[b,:] + bo[i] ----------------
__global__ __launch_bounds__(256) void k_out(const float* __restrict__ op,
                                             const float* __restrict__ Wo,
                                             const float* __restrict__ bo,
                                             float* __restrict__ out) {
  __shared__ __align__(16) float ul[4 * H_];
  int islab = blockIdx.x, bg = blockIdx.y, tid = threadIdx.x;
  #pragma unroll
  for (int k = 0; k < 4; ++k) {
    int idx4 = k * 256 + tid;
    int bl = idx4 >> 8, col4 = idx4 & 255;
    *(float4*)&ul[bl * H_ + col4 * 4] =
        *(const float4*)(op + (size_t)(bg * 4 + bl) * H_ + col4 * 4);
  }
  __syncthreads();
  int i = islab * 256 + tid;
  const float* w = Wo + (size_t)i * H_;
  float acc[4] = {0.f, 0.f, 0.f, 0.f};
  for (int j = 0; j < H_; j += 4) {
    float4 wv = *(const float4*)&w[j];
    #pragma unroll
    for (int bl = 0; bl < 4; ++bl) {
      float4 uv = *(const float4*)&ul[bl * H_ + j];
      acc[bl] += DOT4(uv, wv);
    }
  }
  float bias = bo[i];
  #pragma unroll
  for (int bl = 0; bl < 4; ++bl)
    out[(size_t)(bg * 4 + bl) * H_ + i] = acc[bl] + bias;
}

extern "C" void kernel_launch(void* const* d_in, const int* in_sizes, int n_in,
                              void* d_out, int out_size, void* d_ws, size_t ws_size,
                              hipStream_t stream) {
  const float* x  = (const float*)d_in[0];
  const float* Wq = (const float*)d_in[1];
  const float* bq = (const float*)d_in[2];
  const float* Wk = (const float*)d_in[3];
  const float* bk = (const float*)d_in[4];
  const float* Wv = (const float*)d_in[5];
  const float* bv = (const float*)d_in[6];
  const float* Wo = (const float*)d_in[7];
  const float* bo = (const float*)d_in[8];
  float* out = (float*)d_out;
  float* ws = (float*)d_ws;

  float* q  = ws + Q_OFF;
  float* t  = ws + T_OFF;
  float* c  = ws + C_OFF;
  float* yp = ws + YP_OFF;
  float* ml = ws + ML_OFF;
  float* op = ws + OP_OFF;

  k_q<<<dim3(4, B_ / 4), 256, 0, stream>>>(x, Wq, bq, q);
  k_t<<<dim3(4, NH_), 256, 0, stream>>>(q, Wk, bk, t, c);
  k_flash<<<dim3(NCH, B_), 256, 0, stream>>>(x, t, c, yp, ml);
  k_vproj<<<dim3(NH_, B_ / 4), 256, 0, stream>>>(yp, ml, Wv, bv, op);
  k_out<<<dim3(4, B_ / 4), 256, 0, stream>>>(op, Wo, bo, out);
}

// Round 7
// 387.038 us; speedup vs baseline: 2.9111x; 1.3033x over previous
//
#include <hip/hip_runtime.h>
#include <hip/hip_bf16.h>

#define B_  32
#define S_  4096
#define H_  1024
#define NH_ 16
#define DK_ 64
#define NCH 32                            // chunks of 128 rows
#define ROWS 128
#define TILE 4                            // rows per LDS tile
#define NT (ROWS / TILE)                  // 32 tiles per chunk

// workspace layout (float offsets)
#define Q_OFF  0
#define T_OFF  (Q_OFF + B_*H_)            // q: B*H
#define C_OFF  (T_OFF + B_*NH_*H_)        // t: B*NH*H
#define YP_OFF (C_OFF + B_*NH_)           // c: B*NH
#define ML_OFF (YP_OFF + NCH*B_*NH_*H_)   // y_part: NCH*B*NH*H (64 MB)
#define OP_OFF (ML_OFF + NCH*B_*2*NH_)    // ml stats: NCH*B*2*NH

#define DOT4(a, v) ((a).x*(v).x + (a).y*(v).y + (a).z*(v).z + (a).w*(v).w)

// async global->LDS 16B per lane; LDS base must be wave-uniform
__device__ __forceinline__ void load_lds16(const float* g, float* l) {
  __builtin_amdgcn_global_load_lds(
      (const __attribute__((address_space(1))) void*)g,
      (__attribute__((address_space(3))) void*)l, 16, 0, 0);
}

// ---------------- kernel 1: q[b,i] = x[b,S-1,:] . Wq[i,:] + bq[i] ----------
__global__ __launch_bounds__(256) void k_q(const float* __restrict__ x,
                                           const float* __restrict__ Wq,
                                           const float* __restrict__ bq,
                                           float* __restrict__ q) {
  __shared__ __align__(16) float xl[4 * H_];
  int islab = blockIdx.x, bg = blockIdx.y, tid = threadIdx.x;
  #pragma unroll
  for (int k = 0; k < 4; ++k) {
    int idx4 = k * 256 + tid;
    int bl = idx4 >> 8, col4 = idx4 & 255;
    *(float4*)&xl[bl * H_ + col4 * 4] =
        *(const float4*)(x + (((size_t)(bg * 4 + bl)) * S_ + (S_ - 1)) * H_ + col4 * 4);
  }
  __syncthreads();
  int i = islab * 256 + tid;
  const float* w = Wq + (size_t)i * H_;
  float acc[4] = {0.f, 0.f, 0.f, 0.f};
  for (int j = 0; j < H_; j += 4) {
    float4 wv = *(const float4*)&w[j];
    #pragma unroll
    for (int bl = 0; bl < 4; ++bl) {
      float4 xv = *(const float4*)&xl[bl * H_ + j];
      acc[bl] += DOT4(xv, wv);
    }
  }
  float bias = bq[i];
  #pragma unroll
  for (int bl = 0; bl < 4; ++bl)
    q[(size_t)(bg * 4 + bl) * H_ + i] = acc[bl] + bias;
}

// -------- kernel 2: t[b,h,j] = sum_d q[b,h,d]*Wk[h*64+d, j]; c[b,h]=q.bk ---
__global__ __launch_bounds__(256) void k_t(const float* __restrict__ q,
                                           const float* __restrict__ Wk,
                                           const float* __restrict__ bk,
                                           float* __restrict__ t,
                                           float* __restrict__ c) {
  __shared__ __align__(16) float qh[B_ * DK_];   // 8 KB
  __shared__ __align__(16) float bkh[DK_];
  int js = blockIdx.x, h = blockIdx.y, tid = threadIdx.x;
  #pragma unroll
  for (int k = 0; k < 2; ++k) {
    int idx4 = k * 256 + tid;
    int bl = idx4 >> 4, d4 = idx4 & 15;
    *(float4*)&qh[bl * DK_ + d4 * 4] =
        *(const float4*)(q + (size_t)bl * H_ + h * DK_ + d4 * 4);
  }
  if (tid < 16)
    *(float4*)&bkh[tid * 4] = *(const float4*)(bk + h * DK_ + tid * 4);
  __syncthreads();

  if (js == 0 && tid < B_) {
    float cc = 0.f;
    for (int d = 0; d < DK_; ++d) cc += qh[tid * DK_ + d] * bkh[d];
    c[tid * NH_ + h] = cc;
  }

  int j = js * 256 + tid;
  float acc[B_];
  #pragma unroll
  for (int bl = 0; bl < B_; ++bl) acc[bl] = 0.f;
  for (int d = 0; d < DK_; ++d) {
    float wv = Wk[((size_t)(h * DK_ + d)) * H_ + j];
    #pragma unroll
    for (int bl = 0; bl < B_; ++bl) acc[bl] += qh[bl * DK_ + d] * wv;
  }
  #pragma unroll
  for (int bl = 0; bl < B_; ++bl)
    t[((size_t)(bl * NH_ + h)) * H_ + j] = acc[bl];
}

// ---- kernel 3 (fused flash pass): one read of x computes scores + online
// softmax + weighted x-accumulation. TILE=4 keeps the LDS double-buffer at
// 32 KB -> 3 blocks/CU co-resident (12 waves/CU) to hide barrier/LDS stalls.
__global__ __launch_bounds__(256) void k_flash(const float* __restrict__ x,
                                               const float* __restrict__ t,
                                               const float* __restrict__ c,
                                               float* __restrict__ ypart,
                                               float* __restrict__ mlpart) {
  __shared__ __align__(16) float xb[2][TILE * H_];   // 2 x 16 KB
  __shared__ __align__(16) float eL[TILE][NH_];
  __shared__ float facL[NH_], mL[NH_], lL[NH_], cL[NH_];

  int ch = blockIdx.x, b = blockIdx.y, tid = threadIdx.x;
  int wv = tid >> 6, ln = tid & 63;
  int hh = ln >> 4, cg = ln & 15;
  int h = wv * 4 + hh;
  int lseg = wv * 256;                  // wave's 1KB LDS segment (floats)
  int lsub = ln * 4;                    // lane's float offset in segment

  const float* xg = x + ((size_t)b * S_ + (size_t)ch * ROWS) * H_;

  // t fragment: head h, cols cg*64..cg*64+63, ROTATED order (bank spread).
  float4 tf[16];
  const float* tg = t + ((size_t)b * NH_ + h) * H_ + cg * 64;
  #pragma unroll
  for (int jj = 0; jj < 16; ++jj)
    tf[jj] = *(const float4*)(tg + ((jj + cg) & 15) * 4);

  if (tid < NH_) {
    mL[tid] = -3.4e38f;
    lL[tid] = 0.f;
    cL[tid] = c[b * NH_ + tid];
  }

  float4 ya[NH_];
  #pragma unroll
  for (int h2 = 0; h2 < NH_; ++h2) { ya[h2].x = ya[h2].y = ya[h2].z = ya[h2].w = 0.f; }

  // prologue: async-stage tile 0 -> xb[0]  (TILE*H = 4096 floats = 4 rounds)
  #pragma unroll
  for (int k = 0; k < 4; ++k)
    load_lds16(xg + k * 1024 + lseg + lsub, &xb[0][k * 1024 + lseg]);
  __syncthreads();

  float cL_h = cL[h];

  #pragma unroll 1
  for (int tl = 0; tl < NT; ++tl) {
    int cur = tl & 1;
    // async prefetch of next tile into the other buffer
    if (tl + 1 < NT) {
      const float* xn = xg + (size_t)(tl + 1) * TILE * H_;
      #pragma unroll
      for (int k = 0; k < 4; ++k)
        load_lds16(xn + k * 1024 + lseg + lsub, &xb[cur ^ 1][k * 1024 + lseg]);
    }

    // ---- phase A: scores for TILE rows, head h, cols cg*64..+63 ----
    float scr[TILE];
    #pragma unroll
    for (int s = 0; s < TILE; ++s) scr[s] = 0.f;
    #pragma unroll
    for (int jj = 0; jj < 16; ++jj) {
      int cc = cg * 64 + ((jj + cg) & 15) * 4;
      float4 tv = tf[jj];
      #pragma unroll
      for (int s = 0; s < TILE; ++s) {
        float4 xv = *(const float4*)&xb[cur][s * H_ + cc];
        scr[s] += DOT4(xv, tv);
      }
    }
    #pragma unroll
    for (int s = 0; s < TILE; ++s) {
      float a = scr[s];
      a += __shfl_xor(a, 1);
      a += __shfl_xor(a, 2);
      a += __shfl_xor(a, 4);
      a += __shfl_xor(a, 8);
      scr[s] = (a + cL_h) * 0.125f;
    }
    // online-softmax bookkeeping (redundant across the 16 cg lanes)
    float tmax = scr[0];
    #pragma unroll
    for (int s = 1; s < TILE; ++s) tmax = fmaxf(tmax, scr[s]);
    float mold = mL[h];
    float mnew = fmaxf(mold, tmax);
    float fac = __expf(mold - mnew);
    float es[TILE];
    float sume = 0.f;
    #pragma unroll
    for (int s = 0; s < TILE; ++s) { es[s] = __expf(scr[s] - mnew); sume += es[s]; }
    if (cg == 0) {
      mL[h] = mnew;
      lL[h] = lL[h] * fac + sume;
      facL[h] = fac;
    }
    // lane cg<TILE writes e for row cg (static-select, no dyn reg index)
    float ev = es[0];
    #pragma unroll
    for (int s = 1; s < TILE; ++s) ev = (cg == s) ? es[s] : ev;
    if (cg < TILE) eL[cg][h] = ev;
    __syncthreads();

    // ---- phase B: rescale + accumulate ----
    #pragma unroll
    for (int h2 = 0; h2 < NH_; ++h2) {
      float f2 = facL[h2];
      ya[h2].x *= f2; ya[h2].y *= f2; ya[h2].z *= f2; ya[h2].w *= f2;
    }
    #pragma unroll
    for (int s = 0; s < TILE; ++s) {
      float4 xv = *(const float4*)&xb[cur][s * H_ + tid * 4];
      #pragma unroll
      for (int h4 = 0; h4 < 4; ++h4) {
        float4 e4 = *(const float4*)&eL[s][h4 * 4];
        ya[h4*4+0].x += e4.x * xv.x; ya[h4*4+0].y += e4.x * xv.y;
        ya[h4*4+0].z += e4.x * xv.z; ya[h4*4+0].w += e4.x * xv.w;
        ya[h4*4+1].x += e4.y * xv.x; ya[h4*4+1].y += e4.y * xv.y;
        ya[h4*4+1].z += e4.y * xv.z; ya[h4*4+1].w += e4.y * xv.w;
        ya[h4*4+2].x += e4.z * xv.x; ya[h4*4+2].y += e4.z * xv.y;
        ya[h4*4+2].z += e4.z * xv.z; ya[h4*4+2].w += e4.z * xv.w;
        ya[h4*4+3].x += e4.w * xv.x; ya[h4*4+3].y += e4.w * xv.y;
        ya[h4*4+3].z += e4.w * xv.z; ya[h4*4+3].w += e4.w * xv.w;
      }
    }
    __syncthreads();   // drains async prefetch (vmcnt before barrier)
  }

  // epilogue: partial y + stats
  float* yo = ypart + ((size_t)(ch * B_ + b)) * NH_ * H_ + tid * 4;
  #pragma unroll
  for (int h2 = 0; h2 < NH_; ++h2)
    *(float4*)(yo + (size_t)h2 * H_) = ya[h2];
  if (tid < NH_) {
    mlpart[((size_t)(ch * B_ + b)) * (2 * NH_) + tid * 2 + 0] = mL[tid];
    mlpart[((size_t)(ch * B_ + b)) * (2 * NH_) + tid * 2 + 1] = lL[tid];
  }
}

// -- kernel 4: y[b,h,:] = rescaled sum of y_part / denom; op = Wv.y + bv ----
__global__ __launch_bounds__(256) void k_vproj(const float* __restrict__ ypart,
                                               const float* __restrict__ mlpart,
                                               const float* __restrict__ Wv,
                                               const float* __restrict__ bv,
                                               float* __restrict__ op) {
  __shared__ __align__(16) float yl[4 * H_];
  int h = blockIdx.x, bg = blockIdx.y, tid = threadIdx.x;

  #pragma unroll
  for (int bl = 0; bl < 4; ++bl) {
    int b = bg * 4 + bl;
    float mg = -3.4e38f;
    for (int ch = 0; ch < NCH; ++ch)
      mg = fmaxf(mg, mlpart[((size_t)(ch * B_ + b)) * (2 * NH_) + h * 2]);
    float L = 0.f;
    float4 acc; acc.x = acc.y = acc.z = acc.w = 0.f;
    for (int ch = 0; ch < NCH; ++ch) {
      float mc = mlpart[((size_t)(ch * B_ + b)) * (2 * NH_) + h * 2 + 0];
      float lc = mlpart[((size_t)(ch * B_ + b)) * (2 * NH_) + h * 2 + 1];
      float w = __expf(mc - mg);
      L += w * lc;
      float4 v = *(const float4*)(ypart +
          ((size_t)(ch * B_ + b)) * NH_ * H_ + (size_t)h * H_ + tid * 4);
      acc.x += w * v.x; acc.y += w * v.y; acc.z += w * v.z; acc.w += w * v.w;
    }
    float inv = 1.f / L;
    acc.x *= inv; acc.y *= inv; acc.z *= inv; acc.w *= inv;
    *(float4*)&yl[bl * H_ + tid * 4] = acc;
  }
  __syncthreads();

  int d = tid >> 2, p = tid & 3;
  const float* w = Wv + ((size_t)(h * DK_ + d)) * H_ + p * 256;
  float acc[4] = {0.f, 0.f, 0.f, 0.f};
  for (int jj = 0; jj < 256; jj += 4) {
    float4 wv = *(const float4*)(w + jj);
    #pragma unroll
    for (int bl = 0; bl < 4; ++bl) {
      float4 yv = *(const float4*)&yl[bl * H_ + p * 256 + jj];
      acc[bl] += DOT4(yv, wv);
    }
  }
  #pragma unroll
  for (int bl = 0; bl < 4; ++bl) {
    acc[bl] += __shfl_xor(acc[bl], 1);
    acc[bl] += __shfl_xor(acc[bl], 2);
  }
  if (p == 0) {
    float bias = bv[h * DK_ + d];
    #pragma unroll
    for (int bl = 0; bl < 4; ++bl)
      op[(size_t)(bg * 4 + bl) * H_ + h * DK_ + d] = acc[bl] + bias;
  }
}

// -------- kernel 5: out[b,i] = Wo[i,:].out_pre[b,:] + bo[i] ----------------
__global__ __launch_bounds__(256) void k_out(const float* __restrict__ op,
                                             const float* __restrict__ Wo,
                                             const float* __restrict__ bo,
                                             float* __restrict__ out) {
  __shared__ __align__(16) float ul[4 * H_];
  int islab = blockIdx.x, bg = blockIdx.y, tid = threadIdx.x;
  #pragma unroll
  for (int k = 0; k < 4; ++k) {
    int idx4 = k * 256 + tid;
    int bl = idx4 >> 8, col4 = idx4 & 255;
    *(float4*)&ul[bl * H_ + col4 * 4] =
        *(const float4*)(op + (size_t)(bg * 4 + bl) * H_ + col4 * 4);
  }
  __syncthreads();
  int i = islab * 256 + tid;
  const float* w = Wo + (size_t)i * H_;
  float acc[4] = {0.f, 0.f, 0.f, 0.f};
  for (int j = 0; j < H_; j += 4) {
    float4 wv = *(const float4*)&w[j];
    #pragma unroll
    for (int bl = 0; bl < 4; ++bl) {
      float4 uv = *(const float4*)&ul[bl * H_ + j];
      acc[bl] += DOT4(uv, wv);
    }
  }
  float bias = bo[i];
  #pragma unroll
  for (int bl = 0; bl < 4; ++bl)
    out[(size_t)(bg * 4 + bl) * H_ + i] = acc[bl] + bias;
}

extern "C" void kernel_launch(void* const* d_in, const int* in_sizes, int n_in,
                              void* d_out, int out_size, void* d_ws, size_t ws_size,
                              hipStream_t stream) {
  const float* x  = (const float*)d_in[0];
  const float* Wq = (const float*)d_in[1];
  const float* bq = (const float*)d_in[2];
  const float* Wk = (const float*)d_in[3];
  const float* bk = (const float*)d_in[4];
  const float* Wv = (const float*)d_in[5];
  const float* bv = (const float*)d_in[6];
  const float* Wo = (const float*)d_in[7];
  const float* bo = (const float*)d_in[8];
  float* out = (float*)d_out;
  float* ws = (float*)d_ws;

  float* q  = ws + Q_OFF;
  float* t  = ws + T_OFF;
  float* c  = ws + C_OFF;
  float* yp = ws + YP_OFF;
  float* ml = ws + ML_OFF;
  float* op = ws + OP_OFF;

  k_q<<<dim3(4, B_ / 4), 256, 0, stream>>>(x, Wq, bq, q);
  k_t<<<dim3(4, NH_), 256, 0, stream>>>(q, Wk, bk, t, c);
  k_flash<<<dim3(NCH, B_), 256, 0, stream>>>(x, t, c, yp, ml);
  k_vproj<<<dim3(NH_, B_ / 4), 256, 0, stream>>>(yp, ml, Wv, bv, op);
  k_out<<<dim3(4, B_ / 4), 256, 0, stream>>>(op, Wo, bo, out);
}